// Round 5
// baseline (1262.887 us; speedup 1.0000x reference)
//
#include <hip/hip_runtime.h>

typedef unsigned short u16;
typedef unsigned int u32;

__device__ __forceinline__ float bf2f(u16 u) { return __uint_as_float(((u32)u) << 16); }
__device__ __forceinline__ u16 f2bf(float f) {
    u32 b = __float_as_uint(f);
    b += 0x7fffu + ((b >> 16) & 1u);
    return (u16)(b >> 16);
}

// ---------------- diagnostic probes (overwritten by pipeline when healthy) ----
__global__ void probe_mark(float* __restrict__ out, int base, int n, float val) {
    int i = blockIdx.x * blockDim.x + threadIdx.x;
    if (i < n) out[base + i] = val;
}

__global__ void probe_grid(float* __restrict__ out, float val) {
    if (blockIdx.x == gridDim.x - 1 && threadIdx.x < 64)
        out[64 + threadIdx.x] = val;
}

__global__ void probe_lds(float* __restrict__ out) {
    __shared__ float s[256];
    int t = threadIdx.x;
    s[t] = (float)t;
    __syncthreads();
    float v = s[255 - t];
    float w = __shfl_xor(v, 63);
    if (t < 64) {
        float expect = (float)(255 - (t ^ 63));
        out[128 + t] = (w == expect) ? 40000.0f : 30000.0f;
    }
}

__global__ void probe_ws(float* __restrict__ out, u32* __restrict__ lo, u32* __restrict__ hi, int ws_ok) {
    int t = threadIdx.x;  // 64 threads
    lo[t] = 0x1234000u + t;
    hi[t] = 0xABCD000u + t;
    u32 a = lo[t], b = hi[t];
    int ok = (a == 0x1234000u + t) && (b == 0xABCD000u + t);
    out[192 + t] = !ok ? 35000.0f : (ws_ok ? 80000.0f : 60000.0f);
}

// ---------------- pipeline ----------------
__global__ void zero_fill(u32* __restrict__ p, int n) {
    int i = blockIdx.x * blockDim.x + threadIdx.x;
    if (i < n) p[i] = 0u;
}

// fold attention vectors into W; sum biases. (all fp32)
__global__ void prep_kernel(const float* __restrict__ Ws, const float* __restrict__ att_src,
                            const float* __restrict__ att_dst, const float* __restrict__ biases,
                            float* __restrict__ w_d_all, float* __restrict__ w_s_st,
                            float* __restrict__ w_s_ma, float* __restrict__ w_s_ro,
                            float* __restrict__ bias_sum) {
    int b = blockIdx.x;
    if (b < 5) {
        int k = threadIdx.x;
        if (k >= 128) return;
        const float* Wr = Ws + (size_t)b * 128 * 256 + (size_t)k * 256;
        for (int h = 0; h < 4; ++h) {
            float ss = 0.f, sd = 0.f;
            for (int c = 0; c < 64; ++c) {
                float w = Wr[h * 64 + c];
                ss += w * att_src[(b * 4 + h) * 64 + c];
                sd += w * att_dst[(b * 4 + h) * 64 + c];
            }
            w_d_all[k * 20 + b * 4 + h] = sd;
            if (b < 2)      w_s_st[k * 8 + b * 4 + h] = ss;
            else if (b < 4) w_s_ma[k * 8 + (b - 2) * 4 + h] = ss;
            else            w_s_ro[k * 4 + h] = ss;
        }
    } else if (threadIdx.x < 256) {
        float s = 0.f;
        for (int r = 0; r < 5; ++r) s += biases[r * 256 + threadIdx.x];
        bias_sum[threadIdx.x] = s;
    }
}

// out[N][Kout] = A[N][128] @ W[128][Kout], all fp32, W tiny (L1-resident)
__global__ void skinny_gemm(const float* __restrict__ A, const float* __restrict__ W,
                            float* __restrict__ out, int N, int Kout) {
    int idx = blockIdx.x * blockDim.x + threadIdx.x;
    int row = idx / Kout, col = idx - row * Kout;
    if (row >= N) return;
    const float* a = A + (size_t)row * 128;
    float s = 0.f;
    for (int k = 0; k < 128; ++k) s += a[k] * W[k * Kout + col];
    out[(size_t)row * Kout + col] = s;
}

// C[N][256] = A[N][128] @ W[128][256]; one wave handles 8 rows, lane owns 4 cols.
__global__ __launch_bounds__(256) void gemm8_f32(const float* __restrict__ A, const float* __restrict__ W,
                                                 float* __restrict__ C, int N) {
    int wid = blockIdx.x * 4 + (threadIdx.x >> 6);
    int lane = threadIdx.x & 63;
    int r0 = wid * 8;
    if (r0 >= N) return;
    float acc[8][4] = {};
    for (int k = 0; k < 128; ++k) {
        float4 wv = *(const float4*)(W + (size_t)k * 256 + lane * 4);
        for (int r = 0; r < 8; ++r) {
            int row = r0 + r;
            float a = (row < N) ? A[(size_t)row * 128 + k] : 0.f;
            acc[r][0] += a * wv.x; acc[r][1] += a * wv.y;
            acc[r][2] += a * wv.z; acc[r][3] += a * wv.w;
        }
    }
    for (int r = 0; r < 8; ++r) {
        int row = r0 + r;
        if (row >= N) break;
        float4 o;
        o.x = acc[r][0]; o.y = acc[r][1]; o.z = acc[r][2]; o.w = acc[r][3];
        *(float4*)(C + (size_t)row * 256 + lane * 4) = o;
    }
}

// same but stores bf16 (internal hs buffers)
__global__ __launch_bounds__(256) void gemm8_bf16(const float* __restrict__ A, const float* __restrict__ W,
                                                  u16* __restrict__ C, int N) {
    int wid = blockIdx.x * 4 + (threadIdx.x >> 6);
    int lane = threadIdx.x & 63;
    int r0 = wid * 8;
    if (r0 >= N) return;
    float acc[8][4] = {};
    for (int k = 0; k < 128; ++k) {
        float4 wv = *(const float4*)(W + (size_t)k * 256 + lane * 4);
        for (int r = 0; r < 8; ++r) {
            int row = r0 + r;
            float a = (row < N) ? A[(size_t)row * 128 + k] : 0.f;
            acc[r][0] += a * wv.x; acc[r][1] += a * wv.y;
            acc[r][2] += a * wv.z; acc[r][3] += a * wv.w;
        }
    }
    for (int r = 0; r < 8; ++r) {
        int row = r0 + r;
        if (row >= N) break;
        ushort4 o;
        o.x = f2bf(acc[r][0]); o.y = f2bf(acc[r][1]);
        o.z = f2bf(acc[r][2]); o.w = f2bf(acc[r][3]);
        *(ushort4*)(C + (size_t)row * 256 + lane * 4) = o;
    }
}

// ---------------- CSR build ----------------
__global__ void k_count(const int* __restrict__ dst, u32* __restrict__ cnt, int E) {
    int e = blockIdx.x * blockDim.x + threadIdx.x;
    if (e >= E) return;
    atomicAdd(cnt + dst[e], 1u);
}

__global__ void k_scan1(const u32* __restrict__ cnt, u32* __restrict__ off,
                        u32* __restrict__ bsum, int NJPAD, int nblk) {
    int r = blockIdx.y, b = blockIdx.x, t = threadIdx.x;
    size_t base = (size_t)r * NJPAD + b * 1024 + t * 4;
    u32 v0 = cnt[base], v1 = cnt[base + 1], v2 = cnt[base + 2], v3 = cnt[base + 3];
    u32 tsum = v0 + v1 + v2 + v3;
    __shared__ u32 s[256];
    u32 x = tsum;
    s[t] = x; __syncthreads();
    for (int ofs = 1; ofs < 256; ofs <<= 1) {
        u32 y = (t >= ofs) ? s[t - ofs] : 0u;
        __syncthreads();
        x += y; s[t] = x;
        __syncthreads();
    }
    u32 ex = x - tsum;
    off[base] = ex; off[base + 1] = ex + v0; off[base + 2] = ex + v0 + v1; off[base + 3] = ex + v0 + v1 + v2;
    if (t == 255) bsum[r * nblk + b] = x;
}

__global__ void k_scan2(u32* __restrict__ bsum, int nblk) {
    int r = blockIdx.x, t = threadIdx.x;  // blockDim = 128, nblk <= 128
    u32 v = (t < nblk) ? bsum[r * nblk + t] : 0u;
    __shared__ u32 s[128];
    u32 x = v;
    s[t] = x; __syncthreads();
    for (int ofs = 1; ofs < 128; ofs <<= 1) {
        u32 y = (t >= ofs) ? s[t - ofs] : 0u;
        __syncthreads();
        x += y; s[t] = x;
        __syncthreads();
    }
    if (t < nblk) bsum[r * nblk + t] = x - v;
}

__global__ void k_scan3(u32* __restrict__ off, const u32* __restrict__ bsum, int NJPAD, int nblk) {
    int r = blockIdx.y, b = blockIdx.x, t = threadIdx.x;
    u32 add = bsum[r * nblk + b];
    size_t base = (size_t)r * NJPAD + b * 1024 + t * 4;
    off[base] += add; off[base + 1] += add; off[base + 2] += add; off[base + 3] += add;
}

__global__ void k_fill(const int* __restrict__ src, const int* __restrict__ dst,
                       const u32* __restrict__ off, u32* __restrict__ cur,
                       int* __restrict__ esrc, int E) {
    int e = blockIdx.x * blockDim.x + threadIdx.x;
    if (e >= E) return;
    int d = dst[e];
    u32 pos = off[d] + atomicAdd(cur + d, 1u);
    esrc[pos] = src[e];
}

// ---------------- fused gather + softmax + residual + ReLU + LN ----------------
__device__ __forceinline__ void gat_rel(int lane, u32 beg, u32 end, float4 adr,
                                        const int* __restrict__ es,
                                        const float* __restrict__ asb, int str,
                                        const u16* __restrict__ hs,
                                        float& acc0, float& acc1, float& acc2, float& acc3) {
    if (end <= beg) return;
    float m0 = -3.4e38f, m1 = -3.4e38f, m2 = -3.4e38f, m3 = -3.4e38f;
    for (u32 e = beg; e < end; ++e) {
        int s = es[e];
        float4 as = *(const float4*)(asb + (size_t)s * str);
        float e0 = as.x + adr.x, e1 = as.y + adr.y, e2 = as.z + adr.z, e3 = as.w + adr.w;
        e0 = e0 > 0.f ? e0 : 0.2f * e0; e1 = e1 > 0.f ? e1 : 0.2f * e1;
        e2 = e2 > 0.f ? e2 : 0.2f * e2; e3 = e3 > 0.f ? e3 : 0.2f * e3;
        m0 = fmaxf(m0, e0); m1 = fmaxf(m1, e1); m2 = fmaxf(m2, e2); m3 = fmaxf(m3, e3);
    }
    float s0 = 0.f, s1 = 0.f, s2 = 0.f, s3 = 0.f;
    for (u32 e = beg; e < end; ++e) {
        int s = es[e];
        float4 as = *(const float4*)(asb + (size_t)s * str);
        float e0 = as.x + adr.x, e1 = as.y + adr.y, e2 = as.z + adr.z, e3 = as.w + adr.w;
        e0 = e0 > 0.f ? e0 : 0.2f * e0; e1 = e1 > 0.f ? e1 : 0.2f * e1;
        e2 = e2 > 0.f ? e2 : 0.2f * e2; e3 = e3 > 0.f ? e3 : 0.2f * e3;
        s0 += __expf(e0 - m0); s1 += __expf(e1 - m1);
        s2 += __expf(e2 - m2); s3 += __expf(e3 - m3);
    }
    float i0 = 1.f / (s0 + 1e-16f), i1 = 1.f / (s1 + 1e-16f);
    float i2 = 1.f / (s2 + 1e-16f), i3 = 1.f / (s3 + 1e-16f);
    for (u32 e = beg; e < end; ++e) {
        int s = es[e];
        float4 as = *(const float4*)(asb + (size_t)s * str);
        float e0 = as.x + adr.x, e1 = as.y + adr.y, e2 = as.z + adr.z, e3 = as.w + adr.w;
        e0 = e0 > 0.f ? e0 : 0.2f * e0; e1 = e1 > 0.f ? e1 : 0.2f * e1;
        e2 = e2 > 0.f ? e2 : 0.2f * e2; e3 = e3 > 0.f ? e3 : 0.2f * e3;
        float w0 = __expf(e0 - m0) * i0, w1 = __expf(e1 - m1) * i1;
        float w2 = __expf(e2 - m2) * i2, w3 = __expf(e3 - m3) * i3;
        float w01 = (lane & 16) ? w1 : w0;
        float w23 = (lane & 16) ? w3 : w2;
        float w = (lane & 32) ? w23 : w01;   // head = lane>>4
        ushort4 hv = *(const ushort4*)(hs + (size_t)s * 256 + lane * 4);
        acc0 += w * bf2f(hv.x); acc1 += w * bf2f(hv.y);
        acc2 += w * bf2f(hv.z); acc3 += w * bf2f(hv.w);
    }
}

// One wave per job row; residual staged in d_out (fp32), read then overwritten.
__global__ __launch_bounds__(256) void k_gather(
        const u32* __restrict__ off, const int* __restrict__ esrc,
        const float* __restrict__ a_d,
        const float* __restrict__ as_st, const float* __restrict__ as_ma,
        const float* __restrict__ as_ro,
        const u16* __restrict__ hs0, const u16* __restrict__ hs1,
        const u16* __restrict__ hs2, const u16* __restrict__ hs3,
        const u16* __restrict__ hs4,
        const float* __restrict__ bias_sum,
        const float* __restrict__ gamma, const float* __restrict__ beta,
        float* __restrict__ out, int NJ, int NJPAD, int E) {
    int row = blockIdx.x * 4 + (threadIdx.x >> 6);
    int lane = threadIdx.x & 63;
    if (row >= NJ) return;
    float acc0 = 0.f, acc1 = 0.f, acc2 = 0.f, acc3 = 0.f;
    const float* adp = a_d + (size_t)row * 20;

    {   float4 adr = *(const float4*)(adp + 0);
        gat_rel(lane, off[(size_t)0 * NJPAD + row], off[(size_t)0 * NJPAD + row + 1], adr,
                esrc + (size_t)0 * E, as_st, 8, hs0, acc0, acc1, acc2, acc3); }
    {   float4 adr = *(const float4*)(adp + 4);
        gat_rel(lane, off[(size_t)1 * NJPAD + row], off[(size_t)1 * NJPAD + row + 1], adr,
                esrc + (size_t)1 * E, as_st + 4, 8, hs1, acc0, acc1, acc2, acc3); }
    {   float4 adr = *(const float4*)(adp + 8);
        gat_rel(lane, off[(size_t)2 * NJPAD + row], off[(size_t)2 * NJPAD + row + 1], adr,
                esrc + (size_t)2 * E, as_ma, 8, hs2, acc0, acc1, acc2, acc3); }
    {   float4 adr = *(const float4*)(adp + 12);
        gat_rel(lane, off[(size_t)3 * NJPAD + row], off[(size_t)3 * NJPAD + row + 1], adr,
                esrc + (size_t)3 * E, as_ma + 4, 8, hs3, acc0, acc1, acc2, acc3); }
    {   float4 adr = *(const float4*)(adp + 16);
        gat_rel(lane, off[(size_t)4 * NJPAD + row], off[(size_t)4 * NJPAD + row + 1], adr,
                esrc + (size_t)4 * E, as_ro, 4, hs4, acc0, acc1, acc2, acc3); }

    float4 rr = *(const float4*)(out + (size_t)row * 256 + lane * 4);
    float4 bb = *(const float4*)(bias_sum + lane * 4);
    float h0 = fmaxf(acc0 + rr.x + bb.x, 0.f);
    float h1 = fmaxf(acc1 + rr.y + bb.y, 0.f);
    float h2 = fmaxf(acc2 + rr.z + bb.z, 0.f);
    float h3 = fmaxf(acc3 + rr.w + bb.w, 0.f);
    float s = h0 + h1 + h2 + h3;
    float s2 = h0 * h0 + h1 * h1 + h2 * h2 + h3 * h3;
    for (int o = 32; o; o >>= 1) {
        s += __shfl_xor(s, o);
        s2 += __shfl_xor(s2, o);
    }
    float mu = s * (1.f / 256.f);
    float var = s2 * (1.f / 256.f) - mu * mu;
    float rs = rsqrtf(var + 1e-5f);
    int c = lane * 4;
    float4 g = *(const float4*)(gamma + c);
    float4 be = *(const float4*)(beta + c);
    float4 o;
    o.x = (h0 - mu) * rs * g.x + be.x;
    o.y = (h1 - mu) * rs * g.y + be.y;
    o.z = (h2 - mu) * rs * g.z + be.z;
    o.w = (h3 - mu) * rs * g.w + be.w;
    *(float4*)(out + (size_t)row * 256 + c) = o;
}

// ---------------------------------------------------------------------------
static size_t align256(size_t x) { return (x + 255) & ~(size_t)255; }

extern "C" void kernel_launch(void* const* d_in, const int* in_sizes, int n_in,
                              void* d_out, int out_size, void* d_ws, size_t ws_size,
                              hipStream_t stream) {
    float* out = (float*)d_out;

    // --- probes (always; overwritten by pipeline when healthy) ---
    probe_mark<<<1, 64, 0, stream>>>(out, 0, 64, 10000.0f);
    probe_grid<<<400, 256, 0, stream>>>(out, 20000.0f);
    probe_lds<<<1, 256, 0, stream>>>(out);

    // --- config check ---
    int NJ = in_sizes[0] / 128, NS = in_sizes[1] / 128, NM = in_sizes[2] / 128, NR = in_sizes[3] / 128;
    int E = in_sizes[4];
    bool cfg_ok = (n_in >= 21)
        && (in_sizes[0] == NJ * 128) && (in_sizes[1] == NS * 128)
        && (in_sizes[2] == NM * 128) && (in_sizes[3] == NR * 128)
        && (out_size == NJ * 256)
        && (in_sizes[5] == E) && (in_sizes[6] == E) && (in_sizes[7] == E)
        && (in_sizes[8] == E) && (in_sizes[9] == E) && (in_sizes[10] == E)
        && (in_sizes[11] == E) && (in_sizes[12] == E) && (in_sizes[13] == E)
        && (in_sizes[14] == 5 * 128 * 256) && (in_sizes[15] == 5 * 4 * 64)
        && (in_sizes[16] == 5 * 4 * 64) && (in_sizes[17] == 5 * 256)
        && (in_sizes[18] == 128 * 256) && (in_sizes[19] == 256) && (in_sizes[20] == 256);
    if (!cfg_ok) {
        probe_mark<<<8, 256, 0, stream>>>(out, 0, 2048, 1000000.0f);
        return;
    }

    const float* x_job = (const float*)d_in[0];
    const float* x_st  = (const float*)d_in[1];
    const float* x_ma  = (const float*)d_in[2];
    const float* x_ro  = (const float*)d_in[3];
    const int* src_a[5] = {(const int*)d_in[4],  (const int*)d_in[6],  (const int*)d_in[8],
                           (const int*)d_in[10], (const int*)d_in[12]};
    const int* dst_a[5] = {(const int*)d_in[5],  (const int*)d_in[7],  (const int*)d_in[9],
                           (const int*)d_in[11], (const int*)d_in[13]};
    const float* Ws      = (const float*)d_in[14];
    const float* att_src = (const float*)d_in[15];
    const float* att_dst = (const float*)d_in[16];
    const float* biases  = (const float*)d_in[17];
    const float* W_res   = (const float*)d_in[18];
    const float* gamma   = (const float*)d_in[19];
    const float* beta    = (const float*)d_in[20];

    int nblk = (NJ + 1023) / 1024;
    int NJPAD = nblk * 1024;

    // --- workspace layout ---
    char* base = (char*)d_ws;
    size_t off_b = 0;
    float* w_d_all  = (float*)(base + off_b); off_b += align256(128 * 20 * 4);
    float* w_s_st   = (float*)(base + off_b); off_b += align256(128 * 8 * 4);
    float* w_s_ma   = (float*)(base + off_b); off_b += align256(128 * 8 * 4);
    float* w_s_ro   = (float*)(base + off_b); off_b += align256(128 * 4 * 4);
    float* bias_sum = (float*)(base + off_b); off_b += align256(256 * 4);
    float* a_d      = (float*)(base + off_b); off_b += align256((size_t)NJ * 20 * 4);
    float* as_st    = (float*)(base + off_b); off_b += align256((size_t)NS * 8 * 4);
    float* as_ma    = (float*)(base + off_b); off_b += align256((size_t)NM * 8 * 4);
    float* as_ro    = (float*)(base + off_b); off_b += align256((size_t)NR * 4 * 4);
    u16*   hs0      = (u16*)(base + off_b);   off_b += align256((size_t)NS * 256 * 2);
    u16*   hs1      = (u16*)(base + off_b);   off_b += align256((size_t)NS * 256 * 2);
    u16*   hs2      = (u16*)(base + off_b);   off_b += align256((size_t)NM * 256 * 2);
    u16*   hs3      = (u16*)(base + off_b);   off_b += align256((size_t)NM * 256 * 2);
    u16*   hs4      = (u16*)(base + off_b);   off_b += align256((size_t)NR * 256 * 2);
    u32*   cnt      = (u32*)(base + off_b);   off_b += align256((size_t)5 * NJPAD * 4);
    u32*   cur      = (u32*)(base + off_b);   off_b += align256((size_t)5 * NJPAD * 4);
    u32*   offs     = (u32*)(base + off_b);   off_b += align256((size_t)5 * NJPAD * 4);
    u32*   bsum     = (u32*)(base + off_b);   off_b += align256((size_t)5 * nblk * 4);
    int*   esrc     = (int*)(base + off_b);   off_b += align256((size_t)5 * E * 4);
    size_t needed = off_b;

    int ws_okf = (ws_size >= needed) ? 1 : 0;
    if (ws_size >= 512) {
        u32* lo = (u32*)d_ws;
        u32* hi = (u32*)((char*)d_ws + ((ws_size - 256) & ~(size_t)255));
        probe_ws<<<1, 64, 0, stream>>>(out, lo, hi, ws_okf);
    } else {
        probe_mark<<<1, 64, 0, stream>>>(out, 192, 64, 50000.0f);
    }
    if (!ws_okf) return;

    // --- pipeline ---
    int zc = 5 * NJPAD;
    zero_fill<<<(zc + 255) / 256, 256, 0, stream>>>(cnt, zc);
    zero_fill<<<(zc + 255) / 256, 256, 0, stream>>>(cur, zc);

    prep_kernel<<<6, 256, 0, stream>>>(Ws, att_src, att_dst, biases,
                                       w_d_all, w_s_st, w_s_ma, w_s_ro, bias_sum);

    skinny_gemm<<<((size_t)NJ * 20 + 255) / 256, 256, 0, stream>>>(x_job, w_d_all, a_d, NJ, 20);
    skinny_gemm<<<((size_t)NS * 8 + 255) / 256, 256, 0, stream>>>(x_st, w_s_st, as_st, NS, 8);
    skinny_gemm<<<((size_t)NM * 8 + 255) / 256, 256, 0, stream>>>(x_ma, w_s_ma, as_ma, NM, 8);
    skinny_gemm<<<((size_t)NR * 4 + 255) / 256, 256, 0, stream>>>(x_ro, w_s_ro, as_ro, NR, 4);

    int blkJ = ((NJ + 7) / 8 + 3) / 4;
    int blkS = ((NS + 7) / 8 + 3) / 4;
    int blkM = ((NM + 7) / 8 + 3) / 4;
    int blkR = ((NR + 7) / 8 + 3) / 4;
    gemm8_f32 <<<blkJ, 256, 0, stream>>>(x_job, W_res, out, NJ);            // residual -> d_out
    gemm8_bf16<<<blkS, 256, 0, stream>>>(x_st, Ws + 0 * 32768, hs0, NS);
    gemm8_bf16<<<blkS, 256, 0, stream>>>(x_st, Ws + 1 * 32768, hs1, NS);
    gemm8_bf16<<<blkM, 256, 0, stream>>>(x_ma, Ws + 2 * 32768, hs2, NM);
    gemm8_bf16<<<blkM, 256, 0, stream>>>(x_ma, Ws + 3 * 32768, hs3, NM);
    gemm8_bf16<<<blkR, 256, 0, stream>>>(x_ro, Ws + 4 * 32768, hs4, NR);

    for (int r = 0; r < 5; ++r)
        k_count<<<(E + 255) / 256, 256, 0, stream>>>(dst_a[r], cnt + (size_t)r * NJPAD, E);
    k_scan1<<<dim3(nblk, 5), 256, 0, stream>>>(cnt, offs, bsum, NJPAD, nblk);
    k_scan2<<<5, 128, 0, stream>>>(bsum, nblk);
    k_scan3<<<dim3(nblk, 5), 256, 0, stream>>>(offs, bsum, NJPAD, nblk);
    for (int r = 0; r < 5; ++r)
        k_fill<<<(E + 255) / 256, 256, 0, stream>>>(src_a[r], dst_a[r],
                                                    offs + (size_t)r * NJPAD,
                                                    cur + (size_t)r * NJPAD,
                                                    esrc + (size_t)r * E, E);

    k_gather<<<(NJ + 3) / 4, 256, 0, stream>>>(offs, esrc, a_d, as_st, as_ma, as_ro,
                                               hs0, hs1, hs2, hs3, hs4, bias_sum,
                                               gamma, beta, out, NJ, NJPAD, E);
}

// Round 6
// 714.258 us; speedup vs baseline: 1.7681x; 1.7681x over previous
//
#include <hip/hip_runtime.h>

typedef unsigned short u16;
typedef unsigned int u32;
typedef __attribute__((ext_vector_type(8))) short s16x8;   // 8 bf16 (4 VGPRs)
typedef __attribute__((ext_vector_type(4))) float f32x4;

__device__ __forceinline__ float bf2f(u16 u) { return __uint_as_float(((u32)u) << 16); }
__device__ __forceinline__ u16 f2bf(float f) {
    u32 b = __float_as_uint(f);
    b += 0x7fffu + ((b >> 16) & 1u);
    return (u16)(b >> 16);
}
__device__ __forceinline__ float pick_head(float4 a, int lane) {
    float lo = (lane & 16) ? a.y : a.x;
    float hi = (lane & 16) ? a.w : a.z;
    return (lane & 32) ? hi : lo;
}

// ---------------- failure markers ----------------
__global__ void probe_mark(float* __restrict__ out, int n, float val) {
    int i = blockIdx.x * blockDim.x + threadIdx.x;
    if (i < n) out[i] = val;
}

// ---------------- conversions ----------------
__global__ void cvt4_f2b(const float* __restrict__ in, u16* __restrict__ out, int n4) {
    int i = blockIdx.x * blockDim.x + threadIdx.x;
    if (i >= n4) return;
    float4 v = ((const float4*)in)[i];
    ushort4 o;
    o.x = f2bf(v.x); o.y = f2bf(v.y); o.z = f2bf(v.z); o.w = f2bf(v.w);
    ((ushort4*)out)[i] = o;
}

// wt[(w*256+c)*128+k] = bf16( w<5 ? Ws[w][k][c] : W_res[k][c] )
__global__ void cvt_weights(const float* __restrict__ Ws, const float* __restrict__ W_res,
                            u16* __restrict__ wt) {
    int i = blockIdx.x * blockDim.x + threadIdx.x;
    if (i >= 6 * 256 * 128) return;
    int k = i & 127;
    int c = (i >> 7) & 255;
    int w = i >> 15;
    float v = (w < 5) ? Ws[(size_t)w * 32768 + k * 256 + c] : W_res[k * 256 + c];
    wt[i] = f2bf(v);
}

// ---------------- small prep ----------------
__global__ void zero_fill(u32* __restrict__ p, int n) {
    int i = blockIdx.x * blockDim.x + threadIdx.x;
    if (i < n) p[i] = 0u;
}

__global__ void prep_kernel(const float* __restrict__ Ws, const float* __restrict__ att_src,
                            const float* __restrict__ att_dst, const float* __restrict__ biases,
                            float* __restrict__ w_d_all, float* __restrict__ w_s_st,
                            float* __restrict__ w_s_ma, float* __restrict__ w_s_ro,
                            float* __restrict__ bias_sum) {
    int b = blockIdx.x;
    if (b < 5) {
        int k = threadIdx.x;
        if (k >= 128) return;
        const float* Wr = Ws + (size_t)b * 128 * 256 + (size_t)k * 256;
        for (int h = 0; h < 4; ++h) {
            float ss = 0.f, sd = 0.f;
            for (int c = 0; c < 64; ++c) {
                float w = Wr[h * 64 + c];
                ss += w * att_src[(b * 4 + h) * 64 + c];
                sd += w * att_dst[(b * 4 + h) * 64 + c];
            }
            w_d_all[k * 20 + b * 4 + h] = sd;
            if (b < 2)      w_s_st[k * 8 + b * 4 + h] = ss;
            else if (b < 4) w_s_ma[k * 8 + (b - 2) * 4 + h] = ss;
            else            w_s_ro[k * 4 + h] = ss;
        }
    } else if (threadIdx.x < 256) {
        float s = 0.f;
        for (int r = 0; r < 5; ++r) s += biases[r * 256 + threadIdx.x];
        bias_sum[threadIdx.x] = s;
    }
}

// out[N][Kout] = A[N][128] @ W[128][Kout], fp32, W tiny (cache-resident)
__global__ void skinny_gemm(const float* __restrict__ A, const float* __restrict__ W,
                            float* __restrict__ out, int N, int Kout) {
    int idx = blockIdx.x * blockDim.x + threadIdx.x;
    int row = idx / Kout, col = idx - row * Kout;
    if (row >= N) return;
    const float* a = A + (size_t)row * 128;
    float s = 0.f;
    for (int k = 0; k < 128; ++k) s += a[k] * W[k * Kout + col];
    out[(size_t)row * Kout + col] = s;
}

// ---------------- MFMA GEMM ----------------
// C[N][256] = A[N][128](bf16) @ W[128][256]; Bt = W^T as bf16 [256][128].
// 64x64 tile/block, 4 waves, mfma_f32_16x16x32_bf16. LDS 2*17408 = 34816 B.
__global__ __launch_bounds__(256) void gemm_mfma(const u16* __restrict__ A, const u16* __restrict__ Bt,
                                                 float* __restrict__ Cf, u16* __restrict__ Cb, int N) {
    __shared__ __align__(16) u16 sA[64][136];
    __shared__ __align__(16) u16 sB[64][136];
    int R0 = blockIdx.x * 64;
    int c0 = blockIdx.y * 64;
    int t = threadIdx.x;
    {   // stage A: thread t -> tile row t>>2, 32 bf16 at seg (t&3)*32
        int r = t >> 2, seg = (t & 3) * 32;
        uint4 v0, v1, v2, v3;
        if (R0 + r < N) {
            const uint4* p = (const uint4*)(A + (size_t)(R0 + r) * 128 + seg);
            v0 = p[0]; v1 = p[1]; v2 = p[2]; v3 = p[3];
        } else {
            v0 = v1 = v2 = v3 = make_uint4(0, 0, 0, 0);
        }
        uint4* q = (uint4*)&sA[r][seg];
        q[0] = v0; q[1] = v1; q[2] = v2; q[3] = v3;
        // stage B: same pattern from Bt rows c0..c0+63 (always in-bounds, 256 rows)
        const uint4* pb = (const uint4*)(Bt + (size_t)(c0 + r) * 128 + seg);
        uint4 b0 = pb[0], b1 = pb[1], b2 = pb[2], b3 = pb[3];
        uint4* qb = (uint4*)&sB[r][seg];
        qb[0] = b0; qb[1] = b1; qb[2] = b2; qb[3] = b3;
    }
    __syncthreads();

    int wave = t >> 6, lane = t & 63;
    int quad = lane >> 4, m = lane & 15;
    f32x4 acc[4] = {};
    const u16* aRow = &sA[wave * 16 + m][0];
#pragma unroll
    for (int k0 = 0; k0 < 128; k0 += 32) {
        s16x8 af = *(const s16x8*)(aRow + k0 + quad * 8);
#pragma unroll
        for (int ct = 0; ct < 4; ++ct) {
            s16x8 bf = *(const s16x8*)(&sB[ct * 16 + m][k0 + quad * 8]);
            acc[ct] = __builtin_amdgcn_mfma_f32_16x16x32_bf16(af, bf, acc[ct], 0, 0, 0);
        }
    }
    // C/D: col = lane&15, row = (lane>>4)*4 + reg   [m89-verified]
#pragma unroll
    for (int ct = 0; ct < 4; ++ct) {
#pragma unroll
        for (int i = 0; i < 4; ++i) {
            int row = R0 + wave * 16 + quad * 4 + i;
            if (row < N) {
                size_t idx = (size_t)row * 256 + c0 + ct * 16 + m;
                if (Cf) Cf[idx] = acc[ct][i];
                else    Cb[idx] = f2bf(acc[ct][i]);
            }
        }
    }
}

// ---------------- CSR build ----------------
struct EdgeP { const int* src[5]; const int* dst[5]; };

__global__ void k_count(EdgeP P, u32* __restrict__ cnt, int E, int NJPAD) {
    int r = blockIdx.y;
    int e = blockIdx.x * blockDim.x + threadIdx.x;
    if (e >= E) return;
    atomicAdd(cnt + (size_t)r * NJPAD + P.dst[r][e], 1u);
}

__global__ void k_scan1(const u32* __restrict__ cnt, u32* __restrict__ off,
                        u32* __restrict__ bsum, int NJPAD, int nblk) {
    int r = blockIdx.y, b = blockIdx.x, t = threadIdx.x;
    size_t base = (size_t)r * NJPAD + b * 1024 + t * 4;
    u32 v0 = cnt[base], v1 = cnt[base + 1], v2 = cnt[base + 2], v3 = cnt[base + 3];
    u32 tsum = v0 + v1 + v2 + v3;
    __shared__ u32 s[256];
    u32 x = tsum;
    s[t] = x; __syncthreads();
    for (int ofs = 1; ofs < 256; ofs <<= 1) {
        u32 y = (t >= ofs) ? s[t - ofs] : 0u;
        __syncthreads();
        x += y; s[t] = x;
        __syncthreads();
    }
    u32 ex = x - tsum;
    off[base] = ex; off[base + 1] = ex + v0; off[base + 2] = ex + v0 + v1; off[base + 3] = ex + v0 + v1 + v2;
    if (t == 255) bsum[r * nblk + b] = x;
}

__global__ void k_scan2(u32* __restrict__ bsum, int nblk) {
    int r = blockIdx.x, t = threadIdx.x;  // blockDim=128, nblk<=128
    u32 v = (t < nblk) ? bsum[r * nblk + t] : 0u;
    __shared__ u32 s[128];
    u32 x = v;
    s[t] = x; __syncthreads();
    for (int ofs = 1; ofs < 128; ofs <<= 1) {
        u32 y = (t >= ofs) ? s[t - ofs] : 0u;
        __syncthreads();
        x += y; s[t] = x;
        __syncthreads();
    }
    if (t < nblk) bsum[r * nblk + t] = x - v;
}

__global__ void k_scan3(u32* __restrict__ off, const u32* __restrict__ bsum, int NJPAD, int nblk) {
    int r = blockIdx.y, b = blockIdx.x, t = threadIdx.x;
    u32 add = bsum[r * nblk + b];
    size_t base = (size_t)r * NJPAD + b * 1024 + t * 4;
    off[base] += add; off[base + 1] += add; off[base + 2] += add; off[base + 3] += add;
}

__global__ void k_fill(EdgeP P, const u32* __restrict__ off, u32* __restrict__ cur,
                       int* __restrict__ esrc, int E, int NJPAD) {
    int r = blockIdx.y;
    int e = blockIdx.x * blockDim.x + threadIdx.x;
    if (e >= E) return;
    int d = P.dst[r][e];
    u32 pos = off[(size_t)r * NJPAD + d] + atomicAdd(cur + (size_t)r * NJPAD + d, 1u);
    esrc[(size_t)r * E + pos] = P.src[r][e];
}

// ---------------- softmax precompute: one thread per (row, relation) ----------------
// alpha[r*E + pos] = exp(e - m) per head (float4); denominv[r*NJ + row] = 1/(sum+eps)
__global__ void k_alpha(const u32* __restrict__ offs, const int* __restrict__ esrc,
                        const float* __restrict__ a_d,
                        const float* __restrict__ as_st, const float* __restrict__ as_ma,
                        const float* __restrict__ as_ro,
                        float4* __restrict__ alpha, float4* __restrict__ denominv,
                        int NJ, int NJPAD, int E) {
    int row = blockIdx.x * blockDim.x + threadIdx.x;
    int r = blockIdx.y;
    if (row >= NJ) return;
    const float* asb; int str, ofs;
    if (r == 0)      { asb = as_st; str = 8; ofs = 0; }
    else if (r == 1) { asb = as_st; str = 8; ofs = 4; }
    else if (r == 2) { asb = as_ma; str = 8; ofs = 0; }
    else if (r == 3) { asb = as_ma; str = 8; ofs = 4; }
    else             { asb = as_ro; str = 4; ofs = 0; }
    u32 beg = offs[(size_t)r * NJPAD + row];
    u32 end = offs[(size_t)r * NJPAD + row + 1];
    float4 iv = make_float4(0.f, 0.f, 0.f, 0.f);
    if (end > beg) {
        const float* adp = a_d + (size_t)row * 20 + r * 4;
        float ad0 = adp[0], ad1 = adp[1], ad2 = adp[2], ad3 = adp[3];
        const int* es = esrc + (size_t)r * E;
        float4* al = alpha + (size_t)r * E;
        float m0 = -3.4e38f, m1 = -3.4e38f, m2 = -3.4e38f, m3 = -3.4e38f;
        for (u32 e = beg; e < end; ++e) {
            int s = es[e];
            const float* ap = asb + (size_t)s * str + ofs;
            float e0 = ap[0] + ad0, e1 = ap[1] + ad1, e2 = ap[2] + ad2, e3 = ap[3] + ad3;
            e0 = e0 > 0.f ? e0 : 0.2f * e0; e1 = e1 > 0.f ? e1 : 0.2f * e1;
            e2 = e2 > 0.f ? e2 : 0.2f * e2; e3 = e3 > 0.f ? e3 : 0.2f * e3;
            al[e] = make_float4(e0, e1, e2, e3);
            m0 = fmaxf(m0, e0); m1 = fmaxf(m1, e1); m2 = fmaxf(m2, e2); m3 = fmaxf(m3, e3);
        }
        float s0 = 0.f, s1 = 0.f, s2 = 0.f, s3 = 0.f;
        for (u32 e = beg; e < end; ++e) {
            float4 v = al[e];
            float x0 = __expf(v.x - m0), x1 = __expf(v.y - m1);
            float x2 = __expf(v.z - m2), x3 = __expf(v.w - m3);
            al[e] = make_float4(x0, x1, x2, x3);
            s0 += x0; s1 += x1; s2 += x2; s3 += x3;
        }
        iv = make_float4(1.f / (s0 + 1e-16f), 1.f / (s1 + 1e-16f),
                         1.f / (s2 + 1e-16f), 1.f / (s3 + 1e-16f));
    }
    denominv[(size_t)r * NJ + row] = iv;
}

// ---------------- single-pass gather + residual + ReLU + LN ----------------
__device__ __forceinline__ void gat1(int lane, u32 beg, u32 end,
                                     const int* __restrict__ es, const float4* __restrict__ al,
                                     float iv, const u16* __restrict__ hs,
                                     float& a0, float& a1, float& a2, float& a3) {
    for (u32 e = beg; e < end; ++e) {
        int s = es[e];
        float w = pick_head(al[e], lane) * iv;
        ushort4 hv = *(const ushort4*)(hs + (size_t)s * 256 + lane * 4);
        a0 += w * bf2f(hv.x); a1 += w * bf2f(hv.y);
        a2 += w * bf2f(hv.z); a3 += w * bf2f(hv.w);
    }
}

__global__ __launch_bounds__(256) void k_gather(
        const u32* __restrict__ offs, const int* __restrict__ esrc,
        const float4* __restrict__ alpha, const float4* __restrict__ denominv,
        const u16* __restrict__ hs0, const u16* __restrict__ hs1,
        const u16* __restrict__ hs2, const u16* __restrict__ hs3,
        const u16* __restrict__ hs4,
        const float* __restrict__ bias_sum,
        const float* __restrict__ gamma, const float* __restrict__ beta,
        float* __restrict__ out, int NJ, int NJPAD, int E) {
    int row = blockIdx.x * 4 + (threadIdx.x >> 6);
    int lane = threadIdx.x & 63;
    if (row >= NJ) return;
    float a0 = 0.f, a1 = 0.f, a2 = 0.f, a3 = 0.f;

    const u16* hs[5] = {hs0, hs1, hs2, hs3, hs4};
#pragma unroll
    for (int r = 0; r < 5; ++r) {
        u32 beg = offs[(size_t)r * NJPAD + row];
        u32 end = offs[(size_t)r * NJPAD + row + 1];
        if (end <= beg) continue;
        float iv = pick_head(denominv[(size_t)r * NJ + row], lane);
        gat1(lane, beg, end, esrc + (size_t)r * E, alpha + (size_t)r * E, iv, hs[r], a0, a1, a2, a3);
    }

    float4 rr = *(const float4*)(out + (size_t)row * 256 + lane * 4);   // residual staged in d_out
    float4 bb = *(const float4*)(bias_sum + lane * 4);
    float h0 = fmaxf(a0 + rr.x + bb.x, 0.f);
    float h1 = fmaxf(a1 + rr.y + bb.y, 0.f);
    float h2 = fmaxf(a2 + rr.z + bb.z, 0.f);
    float h3 = fmaxf(a3 + rr.w + bb.w, 0.f);
    float s = h0 + h1 + h2 + h3;
    float s2 = h0 * h0 + h1 * h1 + h2 * h2 + h3 * h3;
    for (int o = 32; o; o >>= 1) {
        s += __shfl_xor(s, o);
        s2 += __shfl_xor(s2, o);
    }
    float mu = s * (1.f / 256.f);
    float var = s2 * (1.f / 256.f) - mu * mu;
    float rs = rsqrtf(var + 1e-5f);
    int c = lane * 4;
    float4 g = *(const float4*)(gamma + c);
    float4 be = *(const float4*)(beta + c);
    float4 o;
    o.x = (h0 - mu) * rs * g.x + be.x;
    o.y = (h1 - mu) * rs * g.y + be.y;
    o.z = (h2 - mu) * rs * g.z + be.z;
    o.w = (h3 - mu) * rs * g.w + be.w;
    *(float4*)(out + (size_t)row * 256 + c) = o;
}

// ---------------------------------------------------------------------------
static size_t align256(size_t x) { return (x + 255) & ~(size_t)255; }

extern "C" void kernel_launch(void* const* d_in, const int* in_sizes, int n_in,
                              void* d_out, int out_size, void* d_ws, size_t ws_size,
                              hipStream_t stream) {
    float* out = (float*)d_out;

    int NJ = in_sizes[0] / 128, NS = in_sizes[1] / 128, NM = in_sizes[2] / 128, NR = in_sizes[3] / 128;
    int E = in_sizes[4];
    bool cfg_ok = (n_in >= 21) && (out_size == NJ * 256)
        && (in_sizes[14] == 5 * 128 * 256) && (in_sizes[18] == 128 * 256)
        && (in_sizes[19] == 256) && (in_sizes[20] == 256);
    if (!cfg_ok) { probe_mark<<<8, 256, 0, stream>>>(out, 2048, 1000000.0f); return; }

    const float* x_job = (const float*)d_in[0];
    const float* x_st  = (const float*)d_in[1];
    const float* x_ma  = (const float*)d_in[2];
    const float* x_ro  = (const float*)d_in[3];
    EdgeP EP;
    EP.src[0] = (const int*)d_in[4];  EP.dst[0] = (const int*)d_in[5];
    EP.src[1] = (const int*)d_in[6];  EP.dst[1] = (const int*)d_in[7];
    EP.src[2] = (const int*)d_in[8];  EP.dst[2] = (const int*)d_in[9];
    EP.src[3] = (const int*)d_in[10]; EP.dst[3] = (const int*)d_in[11];
    EP.src[4] = (const int*)d_in[12]; EP.dst[4] = (const int*)d_in[13];
    const float* Ws      = (const float*)d_in[14];
    const float* att_src = (const float*)d_in[15];
    const float* att_dst = (const float*)d_in[16];
    const float* biases  = (const float*)d_in[17];
    const float* W_res   = (const float*)d_in[18];
    const float* gamma   = (const float*)d_in[19];
    const float* beta    = (const float*)d_in[20];

    int nblk = (NJ + 1023) / 1024;
    int NJPAD = nblk * 1024;

    // --- workspace layout ---
    char* base = (char*)d_ws;
    size_t ob = 0;
    float*  w_d_all  = (float*)(base + ob);  ob += align256(128 * 20 * 4);
    float*  w_s_st   = (float*)(base + ob);  ob += align256(128 * 8 * 4);
    float*  w_s_ma   = (float*)(base + ob);  ob += align256(128 * 8 * 4);
    float*  w_s_ro   = (float*)(base + ob);  ob += align256(128 * 4 * 4);
    float*  bias_sum = (float*)(base + ob);  ob += align256(256 * 4);
    float*  a_d      = (float*)(base + ob);  ob += align256((size_t)NJ * 20 * 4);
    float*  as_st    = (float*)(base + ob);  ob += align256((size_t)NS * 8 * 4);
    float*  as_ma    = (float*)(base + ob);  ob += align256((size_t)NM * 8 * 4);
    float*  as_ro    = (float*)(base + ob);  ob += align256((size_t)NR * 4 * 4);
    u16*    xb_job   = (u16*)(base + ob);    ob += align256((size_t)NJ * 128 * 2);
    u16*    xb_st    = (u16*)(base + ob);    ob += align256((size_t)NS * 128 * 2);
    u16*    xb_ma    = (u16*)(base + ob);    ob += align256((size_t)NM * 128 * 2);
    u16*    xb_ro    = (u16*)(base + ob);    ob += align256((size_t)NR * 128 * 2);
    u16*    wt       = (u16*)(base + ob);    ob += align256((size_t)6 * 256 * 128 * 2);
    u16*    hs0      = (u16*)(base + ob);    ob += align256((size_t)NS * 256 * 2);
    u16*    hs1      = (u16*)(base + ob);    ob += align256((size_t)NS * 256 * 2);
    u16*    hs2      = (u16*)(base + ob);    ob += align256((size_t)NM * 256 * 2);
    u16*    hs3      = (u16*)(base + ob);    ob += align256((size_t)NM * 256 * 2);
    u16*    hs4      = (u16*)(base + ob);    ob += align256((size_t)NR * 256 * 2);
    u32*    cnt      = (u32*)(base + ob);    ob += align256((size_t)5 * NJPAD * 4);
    u32*    cur      = (u32*)(base + ob);    ob += align256((size_t)5 * NJPAD * 4);
    u32*    offs     = (u32*)(base + ob);    ob += align256((size_t)5 * NJPAD * 4);
    u32*    bsum     = (u32*)(base + ob);    ob += align256((size_t)5 * nblk * 4);
    int*    esrc     = (int*)(base + ob);    ob += align256((size_t)5 * E * 4);
    float4* alpha    = (float4*)(base + ob); ob += align256((size_t)5 * E * 16);
    float4* denominv = (float4*)(base + ob); ob += align256((size_t)5 * NJ * 16);

    if (ws_size < ob) { probe_mark<<<8, 256, 0, stream>>>(out, 2048, 500000.0f); return; }

    // --- conversions ---
    cvt4_f2b<<<(NJ * 32 + 255) / 256, 256, 0, stream>>>(x_job, xb_job, NJ * 32);
    cvt4_f2b<<<(NS * 32 + 255) / 256, 256, 0, stream>>>(x_st, xb_st, NS * 32);
    cvt4_f2b<<<(NM * 32 + 255) / 256, 256, 0, stream>>>(x_ma, xb_ma, NM * 32);
    cvt4_f2b<<<(NR * 32 + 255) / 256, 256, 0, stream>>>(x_ro, xb_ro, NR * 32);
    cvt_weights<<<(6 * 256 * 128 + 255) / 256, 256, 0, stream>>>(Ws, W_res, wt);

    int zc = 5 * NJPAD;
    zero_fill<<<(zc + 255) / 256, 256, 0, stream>>>(cnt, zc);
    zero_fill<<<(zc + 255) / 256, 256, 0, stream>>>(cur, zc);

    prep_kernel<<<6, 256, 0, stream>>>(Ws, att_src, att_dst, biases,
                                       w_d_all, w_s_st, w_s_ma, w_s_ro, bias_sum);

    skinny_gemm<<<((size_t)NJ * 20 + 255) / 256, 256, 0, stream>>>(x_job, w_d_all, a_d, NJ, 20);
    skinny_gemm<<<((size_t)NS * 8 + 255) / 256, 256, 0, stream>>>(x_st, w_s_st, as_st, NS, 8);
    skinny_gemm<<<((size_t)NM * 8 + 255) / 256, 256, 0, stream>>>(x_ma, w_s_ma, as_ma, NM, 8);
    skinny_gemm<<<((size_t)NR * 4 + 255) / 256, 256, 0, stream>>>(x_ro, w_s_ro, as_ro, NR, 4);

    // --- MFMA GEMMs (wt row w: weights for relation w; w=5 is W_res) ---
    gemm_mfma<<<dim3((NJ + 63) / 64, 4), 256, 0, stream>>>(xb_job, wt + 5 * 32768, out, (u16*)nullptr, NJ);
    gemm_mfma<<<dim3((NS + 63) / 64, 4), 256, 0, stream>>>(xb_st, wt + 0 * 32768, (float*)nullptr, hs0, NS);
    gemm_mfma<<<dim3((NS + 63) / 64, 4), 256, 0, stream>>>(xb_st, wt + 1 * 32768, (float*)nullptr, hs1, NS);
    gemm_mfma<<<dim3((NM + 63) / 64, 4), 256, 0, stream>>>(xb_ma, wt + 2 * 32768, (float*)nullptr, hs2, NM);
    gemm_mfma<<<dim3((NM + 63) / 64, 4), 256, 0, stream>>>(xb_ma, wt + 3 * 32768, (float*)nullptr, hs3, NM);
    gemm_mfma<<<dim3((NR + 63) / 64, 4), 256, 0, stream>>>(xb_ro, wt + 4 * 32768, (float*)nullptr, hs4, NR);

    // --- CSR build ---
    k_count<<<dim3((E + 255) / 256, 5), 256, 0, stream>>>(EP, cnt, E, NJPAD);
    k_scan1<<<dim3(nblk, 5), 256, 0, stream>>>(cnt, offs, bsum, NJPAD, nblk);
    k_scan2<<<5, 128, 0, stream>>>(bsum, nblk);
    k_scan3<<<dim3(nblk, 5), 256, 0, stream>>>(offs, bsum, NJPAD, nblk);
    k_fill<<<dim3((E + 255) / 256, 5), 256, 0, stream>>>(EP, offs, cur, esrc, E, NJPAD);

    // --- softmax precompute + gather ---
    k_alpha<<<dim3((NJ + 255) / 256, 5), 256, 0, stream>>>(offs, esrc, a_d, as_st, as_ma, as_ro,
                                                           alpha, denominv, NJ, NJPAD, E);
    k_gather<<<(NJ + 3) / 4, 256, 0, stream>>>(offs, esrc, alpha, denominv,
                                               hs0, hs1, hs2, hs3, hs4, bias_sum,
                                               gamma, beta, out, NJ, NJPAD, E);
}

// Round 7
// 646.068 us; speedup vs baseline: 1.9547x; 1.1055x over previous
//
#include <hip/hip_runtime.h>

typedef unsigned short u16;
typedef unsigned int u32;
typedef __attribute__((ext_vector_type(8))) short s16x8;   // 8 bf16 (4 VGPRs)
typedef __attribute__((ext_vector_type(4))) float f32x4;

__device__ __forceinline__ float bf2f(u16 u) { return __uint_as_float(((u32)u) << 16); }
__device__ __forceinline__ u16 f2bf(float f) {
    u32 b = __float_as_uint(f);
    b += 0x7fffu + ((b >> 16) & 1u);
    return (u16)(b >> 16);
}
__device__ __forceinline__ float pick_head(float4 a, int lane) {
    float lo = (lane & 16) ? a.y : a.x;
    float hi = (lane & 16) ? a.w : a.z;
    return (lane & 32) ? hi : lo;
}

__global__ void probe_mark(float* __restrict__ out, int n, float val) {
    int i = blockIdx.x * blockDim.x + threadIdx.x;
    if (i < n) out[i] = val;
}

// ---------------- small prep ----------------
__global__ void zero_fill(u32* __restrict__ p, int n) {
    int i = blockIdx.x * blockDim.x + threadIdx.x;
    if (i < n) p[i] = 0u;
}

// wt[(w*256+c)*128+k] = bf16( w<5 ? Ws[w][k][c] : W_res[k][c] )   (W^T, bf16)
__global__ void cvt_weights(const float* __restrict__ Ws, const float* __restrict__ W_res,
                            u16* __restrict__ wt) {
    int i = blockIdx.x * blockDim.x + threadIdx.x;
    if (i >= 6 * 256 * 128) return;
    int k = i & 127;
    int c = (i >> 7) & 255;
    int w = i >> 15;
    float v = (w < 5) ? Ws[(size_t)w * 32768 + k * 256 + c] : W_res[k * 256 + c];
    wt[i] = f2bf(v);
}

__global__ void prep_kernel(const float* __restrict__ Ws, const float* __restrict__ att_src,
                            const float* __restrict__ att_dst, const float* __restrict__ biases,
                            float* __restrict__ w_d_all, float* __restrict__ w_s_st,
                            float* __restrict__ w_s_ma, float* __restrict__ w_s_ro,
                            float* __restrict__ bias_sum) {
    int b = blockIdx.x;
    if (b < 5) {
        int k = threadIdx.x;
        if (k >= 128) return;
        const float* Wr = Ws + (size_t)b * 128 * 256 + (size_t)k * 256;
        for (int h = 0; h < 4; ++h) {
            float ss = 0.f, sd = 0.f;
            for (int c = 0; c < 64; ++c) {
                float w = Wr[h * 64 + c];
                ss += w * att_src[(b * 4 + h) * 64 + c];
                sd += w * att_dst[(b * 4 + h) * 64 + c];
            }
            w_d_all[k * 20 + b * 4 + h] = sd;
            if (b < 2)      w_s_st[k * 8 + b * 4 + h] = ss;
            else if (b < 4) w_s_ma[k * 8 + (b - 2) * 4 + h] = ss;
            else            w_s_ro[k * 4 + h] = ss;
        }
    } else if (threadIdx.x < 256) {
        float s = 0.f;
        for (int r = 0; r < 5; ++r) s += biases[r * 256 + threadIdx.x];
        bias_sum[threadIdx.x] = s;
    }
}

// ---------------- merged skinny GEMMs (a_s / a_d projections) ----------------
struct SDesc { const float* A; const float* W; float* out; int N; int Kout; int start; };
struct STab { SDesc d[4]; int total; };

__global__ void skinny_all(STab T) {
    int idx = blockIdx.x * blockDim.x + threadIdx.x;
    if (idx >= T.total) return;
    int mi = 0;
    for (int i = 1; i < 4; ++i) if (idx >= T.d[i].start) mi = i;
    SDesc d = T.d[mi];
    int local = idx - d.start;
    int row = local / d.Kout, col = local - row * d.Kout;
    const float* a = d.A + (size_t)row * 128;
    float s = 0.f;
    for (int k = 0; k < 128; ++k) s += a[k] * d.W[k * d.Kout + col];
    d.out[(size_t)row * d.Kout + col] = s;
}

// ---------------- merged MFMA GEMMs ----------------
// C[N][256](bf16) = A[N][128](fp32, converted inline) @ W[128][256](wt slice, bf16 W^T)
struct GDesc { const float* A; u16* C; int wslice; int N; int start; };
struct GTab { GDesc d[6]; };

__global__ __launch_bounds__(256) void gemm_all(GTab T, const u16* __restrict__ wt) {
    __shared__ __align__(16) u16 sA[64][136];
    __shared__ __align__(16) u16 sB[64][136];
    int bx = blockIdx.x;
    int mi = 0;
#pragma unroll
    for (int i = 1; i < 6; ++i) if (bx >= T.d[i].start) mi = i;
    GDesc d = T.d[mi];
    int R0 = (bx - d.start) * 64;
    int c0 = blockIdx.y * 64;
    int t = threadIdx.x;
    {   // stage A (fp32 -> bf16): thread t -> tile row t>>2, 32 elems at (t&3)*32
        int r = t >> 2, seg = (t & 3) * 32;
        ushort4 o[8];
        if (R0 + r < d.N) {
            const float4* p = (const float4*)(d.A + (size_t)(R0 + r) * 128 + seg);
#pragma unroll
            for (int q = 0; q < 8; ++q) {
                float4 v = p[q];
                o[q].x = f2bf(v.x); o[q].y = f2bf(v.y); o[q].z = f2bf(v.z); o[q].w = f2bf(v.w);
            }
        } else {
#pragma unroll
            for (int q = 0; q < 8; ++q) o[q] = make_ushort4(0, 0, 0, 0);
        }
        ushort4* qd = (ushort4*)&sA[r][seg];
#pragma unroll
        for (int q = 0; q < 8; ++q) qd[q] = o[q];
        // stage B: rows c0..c0+63 of Bt[256][128] (always in-bounds)
        const uint4* pb = (const uint4*)(wt + (size_t)d.wslice * 32768 + (size_t)(c0 + r) * 128 + seg);
        uint4 b0 = pb[0], b1 = pb[1], b2 = pb[2], b3 = pb[3];
        uint4* qb = (uint4*)&sB[r][seg];
        qb[0] = b0; qb[1] = b1; qb[2] = b2; qb[3] = b3;
    }
    __syncthreads();

    int wave = t >> 6, lane = t & 63;
    int quad = lane >> 4, m = lane & 15;
    f32x4 acc[4] = {};
    const u16* aRow = &sA[wave * 16 + m][0];
#pragma unroll
    for (int k0 = 0; k0 < 128; k0 += 32) {
        s16x8 af = *(const s16x8*)(aRow + k0 + quad * 8);
#pragma unroll
        for (int ct = 0; ct < 4; ++ct) {
            s16x8 bf = *(const s16x8*)(&sB[ct * 16 + m][k0 + quad * 8]);
            acc[ct] = __builtin_amdgcn_mfma_f32_16x16x32_bf16(af, bf, acc[ct], 0, 0, 0);
        }
    }
    // C/D: col = lane&15, row = (lane>>4)*4 + reg
#pragma unroll
    for (int ct = 0; ct < 4; ++ct) {
#pragma unroll
        for (int i = 0; i < 4; ++i) {
            int row = R0 + wave * 16 + quad * 4 + i;
            if (row < d.N) d.C[(size_t)row * 256 + c0 + ct * 16 + m] = f2bf(acc[ct][i]);
        }
    }
}

// ---------------- CSR build ----------------
struct EdgeP { const int* src[5]; const int* dst[5]; };

__global__ void k_count(EdgeP P, u32* __restrict__ cnt, int E, int NJPAD) {
    int r = blockIdx.y;
    int e = blockIdx.x * blockDim.x + threadIdx.x;
    if (e >= E) return;
    atomicAdd(cnt + (size_t)r * NJPAD + P.dst[r][e], 1u);
}

__global__ void k_scan1(const u32* __restrict__ cnt, u32* __restrict__ off,
                        u32* __restrict__ bsum, int NJPAD, int nblk) {
    int r = blockIdx.y, b = blockIdx.x, t = threadIdx.x;
    size_t base = (size_t)r * NJPAD + b * 1024 + t * 4;
    u32 v0 = cnt[base], v1 = cnt[base + 1], v2 = cnt[base + 2], v3 = cnt[base + 3];
    u32 tsum = v0 + v1 + v2 + v3;
    __shared__ u32 s[256];
    u32 x = tsum;
    s[t] = x; __syncthreads();
    for (int ofs = 1; ofs < 256; ofs <<= 1) {
        u32 y = (t >= ofs) ? s[t - ofs] : 0u;
        __syncthreads();
        x += y; s[t] = x;
        __syncthreads();
    }
    u32 ex = x - tsum;
    off[base] = ex; off[base + 1] = ex + v0; off[base + 2] = ex + v0 + v1; off[base + 3] = ex + v0 + v1 + v2;
    if (t == 255) bsum[r * nblk + b] = x;
}

__global__ void k_scan2(u32* __restrict__ bsum, int nblk) {
    int r = blockIdx.x, t = threadIdx.x;  // blockDim=128, nblk<=128
    u32 v = (t < nblk) ? bsum[r * nblk + t] : 0u;
    __shared__ u32 s[128];
    u32 x = v;
    s[t] = x; __syncthreads();
    for (int ofs = 1; ofs < 128; ofs <<= 1) {
        u32 y = (t >= ofs) ? s[t - ofs] : 0u;
        __syncthreads();
        x += y; s[t] = x;
        __syncthreads();
    }
    if (t < nblk) bsum[r * nblk + t] = x - v;
}

__global__ void k_scan3(u32* __restrict__ off, const u32* __restrict__ bsum, int NJPAD, int nblk) {
    int r = blockIdx.y, b = blockIdx.x, t = threadIdx.x;
    u32 add = bsum[r * nblk + b];
    size_t base = (size_t)r * NJPAD + b * 1024 + t * 4;
    off[base] += add; off[base + 1] += add; off[base + 2] += add; off[base + 3] += add;
}

__global__ void k_fill(EdgeP P, const u32* __restrict__ off, u32* __restrict__ cur,
                       int* __restrict__ esrc, int E, int NJPAD) {
    int r = blockIdx.y;
    int e = blockIdx.x * blockDim.x + threadIdx.x;
    if (e >= E) return;
    int d = P.dst[r][e];
    u32 pos = off[(size_t)r * NJPAD + d] + atomicAdd(cur + (size_t)r * NJPAD + d, 1u);
    esrc[(size_t)r * E + pos] = P.src[r][e];
}

// ---------------- softmax precompute: one thread per (row, relation) ----------------
__global__ void k_alpha(const u32* __restrict__ offs, const int* __restrict__ esrc,
                        const float* __restrict__ a_d,
                        const float* __restrict__ as_st, const float* __restrict__ as_ma,
                        const float* __restrict__ as_ro,
                        float4* __restrict__ alpha, float4* __restrict__ denominv,
                        int NJ, int NJPAD, int E) {
    int row = blockIdx.x * blockDim.x + threadIdx.x;
    int r = blockIdx.y;
    if (row >= NJ) return;
    const float* asb; int str, ofs;
    if (r == 0)      { asb = as_st; str = 8; ofs = 0; }
    else if (r == 1) { asb = as_st; str = 8; ofs = 4; }
    else if (r == 2) { asb = as_ma; str = 8; ofs = 0; }
    else if (r == 3) { asb = as_ma; str = 8; ofs = 4; }
    else             { asb = as_ro; str = 4; ofs = 0; }
    u32 beg = offs[(size_t)r * NJPAD + row];
    u32 end = offs[(size_t)r * NJPAD + row + 1];
    float4 iv = make_float4(0.f, 0.f, 0.f, 0.f);
    if (end > beg) {
        const float* adp = a_d + (size_t)row * 20 + r * 4;
        float ad0 = adp[0], ad1 = adp[1], ad2 = adp[2], ad3 = adp[3];
        const int* es = esrc + (size_t)r * E;
        float4* al = alpha + (size_t)r * E;
        float m0 = -3.4e38f, m1 = -3.4e38f, m2 = -3.4e38f, m3 = -3.4e38f;
        for (u32 e = beg; e < end; ++e) {
            int s = es[e];
            const float* ap = asb + (size_t)s * str + ofs;
            float e0 = ap[0] + ad0, e1 = ap[1] + ad1, e2 = ap[2] + ad2, e3 = ap[3] + ad3;
            e0 = e0 > 0.f ? e0 : 0.2f * e0; e1 = e1 > 0.f ? e1 : 0.2f * e1;
            e2 = e2 > 0.f ? e2 : 0.2f * e2; e3 = e3 > 0.f ? e3 : 0.2f * e3;
            al[e] = make_float4(e0, e1, e2, e3);
            m0 = fmaxf(m0, e0); m1 = fmaxf(m1, e1); m2 = fmaxf(m2, e2); m3 = fmaxf(m3, e3);
        }
        float s0 = 0.f, s1 = 0.f, s2 = 0.f, s3 = 0.f;
        for (u32 e = beg; e < end; ++e) {
            float4 v = al[e];
            float x0 = __expf(v.x - m0), x1 = __expf(v.y - m1);
            float x2 = __expf(v.z - m2), x3 = __expf(v.w - m3);
            al[e] = make_float4(x0, x1, x2, x3);
            s0 += x0; s1 += x1; s2 += x2; s3 += x3;
        }
        iv = make_float4(1.f / (s0 + 1e-16f), 1.f / (s1 + 1e-16f),
                         1.f / (s2 + 1e-16f), 1.f / (s3 + 1e-16f));
    }
    denominv[(size_t)r * NJ + row] = iv;
}

// ---------------- single-pass gather (unroll-4 for MLP) + residual + ReLU + LN ----------------
__device__ __forceinline__ void gat1(int lane, u32 beg, u32 end,
                                     const int* __restrict__ es, const float4* __restrict__ al,
                                     float iv, const u16* __restrict__ hs,
                                     float& a0, float& a1, float& a2, float& a3) {
    u32 e = beg;
    for (; e + 4 <= end; e += 4) {
        int s0 = es[e], s1 = es[e + 1], s2 = es[e + 2], s3 = es[e + 3];
        float4 A0 = al[e], A1 = al[e + 1], A2 = al[e + 2], A3 = al[e + 3];
        ushort4 h0 = *(const ushort4*)(hs + (size_t)s0 * 256 + lane * 4);
        ushort4 h1 = *(const ushort4*)(hs + (size_t)s1 * 256 + lane * 4);
        ushort4 h2 = *(const ushort4*)(hs + (size_t)s2 * 256 + lane * 4);
        ushort4 h3 = *(const ushort4*)(hs + (size_t)s3 * 256 + lane * 4);
        float w0 = pick_head(A0, lane) * iv;
        float w1 = pick_head(A1, lane) * iv;
        float w2 = pick_head(A2, lane) * iv;
        float w3 = pick_head(A3, lane) * iv;
        a0 += w0 * bf2f(h0.x) + w1 * bf2f(h1.x) + w2 * bf2f(h2.x) + w3 * bf2f(h3.x);
        a1 += w0 * bf2f(h0.y) + w1 * bf2f(h1.y) + w2 * bf2f(h2.y) + w3 * bf2f(h3.y);
        a2 += w0 * bf2f(h0.z) + w1 * bf2f(h1.z) + w2 * bf2f(h2.z) + w3 * bf2f(h3.z);
        a3 += w0 * bf2f(h0.w) + w1 * bf2f(h1.w) + w2 * bf2f(h2.w) + w3 * bf2f(h3.w);
    }
    for (; e < end; ++e) {
        int s = es[e];
        float w = pick_head(al[e], lane) * iv;
        ushort4 hv = *(const ushort4*)(hs + (size_t)s * 256 + lane * 4);
        a0 += w * bf2f(hv.x); a1 += w * bf2f(hv.y);
        a2 += w * bf2f(hv.z); a3 += w * bf2f(hv.w);
    }
}

__global__ __launch_bounds__(256) void k_gather(
        const u32* __restrict__ offs, const int* __restrict__ esrc,
        const float4* __restrict__ alpha, const float4* __restrict__ denominv,
        const u16* __restrict__ hs0, const u16* __restrict__ hs1,
        const u16* __restrict__ hs2, const u16* __restrict__ hs3,
        const u16* __restrict__ hs4, const u16* __restrict__ resb,
        const float* __restrict__ bias_sum,
        const float* __restrict__ gamma, const float* __restrict__ beta,
        float* __restrict__ out, int NJ, int NJPAD, int E) {
    int row = blockIdx.x * 4 + (threadIdx.x >> 6);
    int lane = threadIdx.x & 63;
    if (row >= NJ) return;
    float a0 = 0.f, a1 = 0.f, a2 = 0.f, a3 = 0.f;

    const u16* hs[5] = {hs0, hs1, hs2, hs3, hs4};
#pragma unroll
    for (int r = 0; r < 5; ++r) {
        u32 beg = offs[(size_t)r * NJPAD + row];
        u32 end = offs[(size_t)r * NJPAD + row + 1];
        if (end <= beg) continue;
        float iv = pick_head(denominv[(size_t)r * NJ + row], lane);
        gat1(lane, beg, end, esrc + (size_t)r * E, alpha + (size_t)r * E, iv, hs[r], a0, a1, a2, a3);
    }

    ushort4 rr = *(const ushort4*)(resb + (size_t)row * 256 + lane * 4);
    float4 bb = *(const float4*)(bias_sum + lane * 4);
    float h0 = fmaxf(a0 + bf2f(rr.x) + bb.x, 0.f);
    float h1 = fmaxf(a1 + bf2f(rr.y) + bb.y, 0.f);
    float h2 = fmaxf(a2 + bf2f(rr.z) + bb.z, 0.f);
    float h3 = fmaxf(a3 + bf2f(rr.w) + bb.w, 0.f);
    float s = h0 + h1 + h2 + h3;
    float s2 = h0 * h0 + h1 * h1 + h2 * h2 + h3 * h3;
    for (int o = 32; o; o >>= 1) {
        s += __shfl_xor(s, o);
        s2 += __shfl_xor(s2, o);
    }
    float mu = s * (1.f / 256.f);
    float var = s2 * (1.f / 256.f) - mu * mu;
    float rs = rsqrtf(var + 1e-5f);
    int c = lane * 4;
    float4 g = *(const float4*)(gamma + c);
    float4 be = *(const float4*)(beta + c);
    float4 o;
    o.x = (h0 - mu) * rs * g.x + be.x;
    o.y = (h1 - mu) * rs * g.y + be.y;
    o.z = (h2 - mu) * rs * g.z + be.z;
    o.w = (h3 - mu) * rs * g.w + be.w;
    *(float4*)(out + (size_t)row * 256 + c) = o;
}

// ---------------------------------------------------------------------------
static size_t align256(size_t x) { return (x + 255) & ~(size_t)255; }

extern "C" void kernel_launch(void* const* d_in, const int* in_sizes, int n_in,
                              void* d_out, int out_size, void* d_ws, size_t ws_size,
                              hipStream_t stream) {
    float* out = (float*)d_out;

    int NJ = in_sizes[0] / 128, NS = in_sizes[1] / 128, NM = in_sizes[2] / 128, NR = in_sizes[3] / 128;
    int E = in_sizes[4];
    bool cfg_ok = (n_in >= 21) && (out_size == NJ * 256)
        && (in_sizes[14] == 5 * 128 * 256) && (in_sizes[18] == 128 * 256)
        && (in_sizes[19] == 256) && (in_sizes[20] == 256);
    if (!cfg_ok) { probe_mark<<<8, 256, 0, stream>>>(out, 2048, 1000000.0f); return; }

    const float* x_job = (const float*)d_in[0];
    const float* x_st  = (const float*)d_in[1];
    const float* x_ma  = (const float*)d_in[2];
    const float* x_ro  = (const float*)d_in[3];
    EdgeP EP;
    EP.src[0] = (const int*)d_in[4];  EP.dst[0] = (const int*)d_in[5];
    EP.src[1] = (const int*)d_in[6];  EP.dst[1] = (const int*)d_in[7];
    EP.src[2] = (const int*)d_in[8];  EP.dst[2] = (const int*)d_in[9];
    EP.src[3] = (const int*)d_in[10]; EP.dst[3] = (const int*)d_in[11];
    EP.src[4] = (const int*)d_in[12]; EP.dst[4] = (const int*)d_in[13];
    const float* Ws      = (const float*)d_in[14];
    const float* att_src = (const float*)d_in[15];
    const float* att_dst = (const float*)d_in[16];
    const float* biases  = (const float*)d_in[17];
    const float* W_res   = (const float*)d_in[18];
    const float* gamma   = (const float*)d_in[19];
    const float* beta    = (const float*)d_in[20];

    int nblk = (NJ + 1023) / 1024;
    int NJPAD = nblk * 1024;

    // --- workspace layout ---
    char* base = (char*)d_ws;
    size_t ob = 0;
    float*  w_d_all  = (float*)(base + ob);  ob += align256(128 * 20 * 4);
    float*  w_s_st   = (float*)(base + ob);  ob += align256(128 * 8 * 4);
    float*  w_s_ma   = (float*)(base + ob);  ob += align256(128 * 8 * 4);
    float*  w_s_ro   = (float*)(base + ob);  ob += align256(128 * 4 * 4);
    float*  bias_sum = (float*)(base + ob);  ob += align256(256 * 4);
    float*  a_d      = (float*)(base + ob);  ob += align256((size_t)NJ * 20 * 4);
    float*  as_st    = (float*)(base + ob);  ob += align256((size_t)NS * 8 * 4);
    float*  as_ma    = (float*)(base + ob);  ob += align256((size_t)NM * 8 * 4);
    float*  as_ro    = (float*)(base + ob);  ob += align256((size_t)NR * 4 * 4);
    u16*    wt       = (u16*)(base + ob);    ob += align256((size_t)6 * 256 * 128 * 2);
    u16*    resb     = (u16*)(base + ob);    ob += align256((size_t)NJ * 256 * 2);
    u16*    hs0      = (u16*)(base + ob);    ob += align256((size_t)NS * 256 * 2);
    u16*    hs1      = (u16*)(base + ob);    ob += align256((size_t)NS * 256 * 2);
    u16*    hs2      = (u16*)(base + ob);    ob += align256((size_t)NM * 256 * 2);
    u16*    hs3      = (u16*)(base + ob);    ob += align256((size_t)NM * 256 * 2);
    u16*    hs4      = (u16*)(base + ob);    ob += align256((size_t)NR * 256 * 2);
    u32*    cnt      = (u32*)(base + ob);    ob += align256((size_t)5 * NJPAD * 4);
    u32*    cur      = (u32*)(base + ob);    ob += align256((size_t)5 * NJPAD * 4);
    u32*    offs     = (u32*)(base + ob);    ob += align256((size_t)5 * NJPAD * 4);
    u32*    bsum     = (u32*)(base + ob);    ob += align256((size_t)5 * nblk * 4);
    int*    esrc     = (int*)(base + ob);    ob += align256((size_t)5 * E * 4);
    float4* alpha    = (float4*)(base + ob); ob += align256((size_t)5 * E * 16);
    float4* denominv = (float4*)(base + ob); ob += align256((size_t)5 * NJ * 16);

    if (ws_size < ob) { probe_mark<<<8, 256, 0, stream>>>(out, 2048, 500000.0f); return; }

    // --- zero cnt+cur in one launch (contiguous) ---
    int zc = 2 * 5 * NJPAD;
    zero_fill<<<(zc + 255) / 256, 256, 0, stream>>>(cnt, zc);

    cvt_weights<<<(6 * 256 * 128 + 255) / 256, 256, 0, stream>>>(Ws, W_res, wt);
    prep_kernel<<<6, 256, 0, stream>>>(Ws, att_src, att_dst, biases,
                                       w_d_all, w_s_st, w_s_ma, w_s_ro, bias_sum);

    // --- merged skinny GEMMs ---
    STab ST;
    ST.d[0] = {x_job, w_d_all, a_d, NJ, 20, 0};
    ST.d[1] = {x_st, w_s_st, as_st, NS, 8, NJ * 20};
    ST.d[2] = {x_ma, w_s_ma, as_ma, NM, 8, NJ * 20 + NS * 8};
    ST.d[3] = {x_ro, w_s_ro, as_ro, NR, 4, NJ * 20 + NS * 8 + NM * 8};
    ST.total = NJ * 20 + NS * 8 + NM * 8 + NR * 4;
    skinny_all<<<(ST.total + 255) / 256, 256, 0, stream>>>(ST);

    // --- merged MFMA GEMMs (6 matrices, one launch) ---
    int tJ = (NJ + 63) / 64, tS = (NS + 63) / 64, tM = (NM + 63) / 64, tR = (NR + 63) / 64;
    GTab GT;
    int gs = 0;
    GT.d[0] = {x_job, resb, 5, NJ, gs}; gs += tJ;
    GT.d[1] = {x_st,  hs0,  0, NS, gs}; gs += tS;
    GT.d[2] = {x_st,  hs1,  1, NS, gs}; gs += tS;
    GT.d[3] = {x_ma,  hs2,  2, NM, gs}; gs += tM;
    GT.d[4] = {x_ma,  hs3,  3, NM, gs}; gs += tM;
    GT.d[5] = {x_ro,  hs4,  4, NR, gs}; gs += tR;
    gemm_all<<<dim3(gs, 4), 256, 0, stream>>>(GT, wt);

    // --- CSR build ---
    k_count<<<dim3((E + 255) / 256, 5), 256, 0, stream>>>(EP, cnt, E, NJPAD);
    k_scan1<<<dim3(nblk, 5), 256, 0, stream>>>(cnt, offs, bsum, NJPAD, nblk);
    k_scan2<<<5, 128, 0, stream>>>(bsum, nblk);
    k_scan3<<<dim3(nblk, 5), 256, 0, stream>>>(offs, bsum, NJPAD, nblk);
    k_fill<<<dim3((E + 255) / 256, 5), 256, 0, stream>>>(EP, offs, cur, esrc, E, NJPAD);

    // --- softmax precompute + gather ---
    k_alpha<<<dim3((NJ + 255) / 256, 5), 256, 0, stream>>>(offs, esrc, a_d, as_st, as_ma, as_ro,
                                                           alpha, denominv, NJ, NJPAD, E);
    k_gather<<<(NJ + 3) / 4, 256, 0, stream>>>(offs, esrc, alpha, denominv,
                                               hs0, hs1, hs2, hs3, hs4, resb, bias_sum,
                                               gamma, beta, out, NJ, NJPAD, E);
}